// Round 7
// baseline (306.710 us; speedup 1.0000x reference)
//
#include <hip/hip_runtime.h>
#include <hip/hip_bf16.h>
#include <math.h>

typedef float f32x4 __attribute__((ext_vector_type(4)));
typedef short bh8  __attribute__((ext_vector_type(8)));
typedef unsigned int u32x4 __attribute__((ext_vector_type(4)));

#define B_   16
#define IC   128
#define OC   256
#define RC   128
#define STY  512
#define KS_  3
#define LL   16384
#define LT   128
#define NT_  2          // L-tiles per block

// ws layout (bytes)
#define WS_S_OFF   0
#define WS_W_OFF   8192
#define WS_W1_OFF  (8192 + 3145728)

// One LDS union buffer, phase-overlaid with barriers (per tile):
//   phase A: xs bf16, rows 0..129 = pos l0-1 .. l0+128, stride 256B, XOR ((row&15)<<4)
//   phase B: gs bf16, rows 0..127 = pos, same stride/swizzle
//   phase C: ys bf16 final out, [128 pos][132 ch], stride 264B, no swizzle
#define SMEM_BYTES 33792

__device__ __forceinline__ unsigned short f2b(float f) {
    union { float f; unsigned int u; } z; z.f = f;
    unsigned int u = z.u;
    return (unsigned short)((u + 0x7fffu + ((u >> 16) & 1u)) >> 16);
}

__device__ __forceinline__ float b2f(unsigned int u16) {
    union { unsigned int u; float f; } z; z.u = u16 << 16;
    return z.f;
}

__device__ __forceinline__ unsigned int pack2bf(float a, float b) {
    __hip_bfloat162 p = __float22bfloat162_rn(make_float2(a, b));
    return *(unsigned int*)&p;
}

// ---------------- prologue 1: s[b][i] = style @ (mod_weight*scale).T + bias ----
__global__ void k_style(const float* __restrict__ style, const float* __restrict__ mw,
                        const float* __restrict__ mb, float* __restrict__ s_out) {
    const int b = blockIdx.x, i = threadIdx.x;
    const float4* st = (const float4*)(style + b * STY);
    const float4* w  = (const float4*)(mw + (size_t)i * STY);
    float acc = 0.f;
#pragma unroll 4
    for (int j = 0; j < STY / 4; ++j) {
        float4 a = st[j], c = w[j];
        acc += a.x * c.x + a.y * c.y + a.z * c.z + a.w * c.w;
    }
    s_out[b * IC + i] = acc * 0.044194173824159216f + mb[i];  // 1/sqrt(512)
}

// ---------------- prologue 2: modulated+demodulated bf16 weights ---------------
// wbf[b][o][tap*128 + i]
__global__ void k_modw(const float* __restrict__ cw, const float* __restrict__ s,
                       unsigned short* __restrict__ wbf) {
    const int o = blockIdx.x, b = blockIdx.y, i = threadIdx.x;
    const float sv = s[b * IC + i] * 0.029462782549439476f;  // 1/sqrt(128*9)
    const float w0 = cw[(o * IC + i) * KS_ + 0] * sv;
    const float w1 = cw[(o * IC + i) * KS_ + 1] * sv;
    const float w2 = cw[(o * IC + i) * KS_ + 2] * sv;
    float ss = w0 * w0 + w1 * w1 + w2 * w2;
    for (int off = 32; off; off >>= 1) ss += __shfl_down(ss, off, 64);
    __shared__ float red[2];
    if ((i & 63) == 0) red[i >> 6] = ss;
    __syncthreads();
    const float d = rsqrtf(red[0] + red[1] + 1e-8f);
    unsigned short* dst = wbf + ((size_t)b * OC + o) * 384 + i;
    dst[0]   = f2b(w0 * d);
    dst[128] = f2b(w1 * d);
    dst[256] = f2b(w2 * d);
}

// ---------------- prologue 3: weight-normed 1x1 conv matrix (bf16) -------------
__global__ void k_w1(const float* __restrict__ v, const float* __restrict__ g,
                     unsigned short* __restrict__ w1bf) {
    const int o = blockIdx.x, c = threadIdx.x;
    const float vv = v[o * RC + c];
    float ss = vv * vv;
    for (int off = 32; off; off >>= 1) ss += __shfl_down(ss, off, 64);
    __shared__ float red[2];
    if ((c & 63) == 0) red[c >> 6] = ss;
    __syncthreads();
    w1bf[o * RC + c] = f2b(g[o] * vv * rsqrtf(red[0] + red[1]));
}

// ---------------- main fused kernel -------------------------------------------
__global__ __launch_bounds__(512, 4) void k_main(
    const float* __restrict__ x, const unsigned short* __restrict__ wbf,
    const unsigned short* __restrict__ w1bf, const float* __restrict__ obias,
    float* __restrict__ out) {
    __shared__ alignas(16) char smem[SMEM_BYTES];

    const int t = threadIdx.x;
    const int lane = t & 63, wv = t >> 6;
    const int lm = lane & 15, kg = lane >> 4;
    const int c0 = wv * 16 + kg * 4;

    // ---- XCD-aware remap: XCD k owns batches {2k,2k+1}; block = 2 adjacent tiles
    const int lid = blockIdx.x;          // 0..1023
    const int xcd = lid & 7, idx = lid >> 3;   // idx 0..127
    const int b   = xcd * 2 + (idx >> 6);
    const int l0b = (idx & 63) * (LT * NT_);

    const float* xbase = x + (size_t)b * IC * LL;
    const unsigned short* wa  = wbf + ((size_t)b * OC + wv * 16 + lm) * 384 + kg * 8;
    const unsigned short* wb2 = wa + 128 * 384;
    const unsigned short* w1p = w1bf + (wv * 16 + lm) * RC + kg * 8;

    // prefetch registers for tile 1 (issued during tile 0's compute)
    float pf0[16], pf1[16];   // [p*8+c], h=0 and h=1 channel halves
    float pfh0 = 0.f, pfh1 = 0.f;

#pragma unroll
    for (int tt = 0; tt < NT_; ++tt) {
        const int l0 = l0b + tt * LT;
        const float* xb = xbase + l0;

        if (tt == 1) __syncthreads();  // B6: tile0 ys reads done before overlay

        // ---- staging: xs bf16 transposed, swizzled, packed b128 writes
        if (tt == 0) {
            const int chb = wv * 16;
#pragma unroll
            for (int p = 0; p < 2; ++p) {
                const int pos = lane + p * 64;
                const int row = pos + 1;
#pragma unroll
                for (int h = 0; h < 2; ++h) {
                    float xv[8];
#pragma unroll
                    for (int c = 0; c < 8; ++c)
                        xv[c] = xb[(size_t)(chb + h * 8 + c) * LL + pos];
                    u32x4 wvec;
                    wvec.x = pack2bf(xv[0], xv[1]);
                    wvec.y = pack2bf(xv[2], xv[3]);
                    wvec.z = pack2bf(xv[4], xv[5]);
                    wvec.w = pack2bf(xv[6], xv[7]);
                    *(u32x4*)(smem + row * 256 +
                              (((chb + h * 8) * 2) ^ ((row & 15) << 4))) = wvec;
                }
            }
            if (t < 128) {  // halo: row 0 = l0-1, row 129 = l0+128
                const float* hx = xbase + (size_t)t * LL;
                float lf = (l0 > 0) ? hx[l0 - 1] : 0.f;
                float rt = (l0 + LT < LL) ? hx[l0 + LT] : 0.f;
                *(unsigned short*)(smem + 0 * 256 + ((t * 2) ^ ((0 & 15) << 4)))     = f2b(lf);
                *(unsigned short*)(smem + 129 * 256 + ((t * 2) ^ ((129 & 15) << 4))) = f2b(rt);
            }
        } else {
            const int chb = wv * 16;
#pragma unroll
            for (int p = 0; p < 2; ++p) {
                const int row = lane + p * 64 + 1;
#pragma unroll
                for (int h = 0; h < 2; ++h) {
                    u32x4 wvec;
                    if (h == 0) {
                        wvec.x = pack2bf(pf0[p * 8 + 0], pf0[p * 8 + 1]);
                        wvec.y = pack2bf(pf0[p * 8 + 2], pf0[p * 8 + 3]);
                        wvec.z = pack2bf(pf0[p * 8 + 4], pf0[p * 8 + 5]);
                        wvec.w = pack2bf(pf0[p * 8 + 6], pf0[p * 8 + 7]);
                    } else {
                        wvec.x = pack2bf(pf1[p * 8 + 0], pf1[p * 8 + 1]);
                        wvec.y = pack2bf(pf1[p * 8 + 2], pf1[p * 8 + 3]);
                        wvec.z = pack2bf(pf1[p * 8 + 4], pf1[p * 8 + 5]);
                        wvec.w = pack2bf(pf1[p * 8 + 6], pf1[p * 8 + 7]);
                    }
                    *(u32x4*)(smem + row * 256 +
                              (((chb + h * 8) * 2) ^ ((row & 15) << 4))) = wvec;
                }
            }
            if (t < 128) {
                *(unsigned short*)(smem + 0 * 256 + ((t * 2) ^ ((0 & 15) << 4)))     = f2b(pfh0);
                *(unsigned short*)(smem + 129 * 256 + ((t * 2) ^ ((129 & 15) << 4))) = f2b(pfh1);
            }
        }
        __syncthreads();  // B1

        // ---- issue tile1 prefetch, half 1 (h=0) + halo: hides under conv MFMA
        if (tt == 0) {
            const float* xb1 = xbase + l0b + LT;
#pragma unroll
            for (int p = 0; p < 2; ++p)
#pragma unroll
                for (int c = 0; c < 8; ++c)
                    pf0[p * 8 + c] = xb1[(size_t)(wv * 16 + c) * LL + lane + p * 64];
            if (t < 128) {
                const float* hx = xbase + (size_t)t * LL;
                pfh0 = hx[l0b + LT - 1];
                pfh1 = (l0b + 2 * LT < LL) ? hx[l0b + 2 * LT] : 0.f;
            }
        }

        // ---- conv: M-tiles [16wv,+16) (xa) and [128+16wv,+16) (xb), N=128, K=384
        f32x4 acc[2][8];
#pragma unroll
        for (int m = 0; m < 2; ++m)
#pragma unroll
            for (int nt = 0; nt < 8; ++nt) acc[m][nt] = (f32x4){0.f, 0.f, 0.f, 0.f};

        bh8 ca0 = *(const bh8*)(wa + 0);
        bh8 ca1 = *(const bh8*)(wb2 + 0);
#pragma unroll
        for (int kc = 0; kc < 12; ++kc) {
            bh8 na0 = ca0, na1 = ca1;
            if (kc < 11) {
                const int nkoff = ((kc + 1) >> 2) * 128 + ((kc + 1) & 3) * 32;
                na0 = *(const bh8*)(wa + nkoff);
                na1 = *(const bh8*)(wb2 + nkoff);
            }
            const int tap = kc >> 2;
            const int icb = (kc & 3) * 32;
#pragma unroll
            for (int nt = 0; nt < 8; ++nt) {
                const int lr = nt * 16 + lm + tap;
                const bh8 bf = *(const bh8*)(smem + lr * 256 +
                                             (((icb + kg * 8) * 2) ^ ((lr & 15) << 4)));
                acc[0][nt] = __builtin_amdgcn_mfma_f32_16x16x32_bf16(ca0, bf, acc[0][nt], 0, 0, 0);
                acc[1][nt] = __builtin_amdgcn_mfma_f32_16x16x32_bf16(ca1, bf, acc[1][nt], 0, 0, 0);
            }
            ca0 = na0; ca1 = na1;
        }

        // ---- residual x (bf16) back from XS (before B2)
        unsigned long long xr[8];
#pragma unroll
        for (int nt = 0; nt < 8; ++nt) {
            const int row = nt * 16 + lm + 1;
            xr[nt] = *(const unsigned long long*)(smem + row * 256 +
                                                 ((c0 * 2) ^ ((row & 15) << 4)));
        }

        // ---- 1x1 weights (L1/L2-hot on second tile)
        bh8 w1f[4];
#pragma unroll
        for (int kc = 0; kc < 4; ++kc) w1f[kc] = *(const bh8*)(w1p + kc * 32);

        // ---- gated tanh-sigmoid in registers
        unsigned long long gw[8];
#pragma unroll
        for (int nt = 0; nt < 8; ++nt) {
            float g4[4];
#pragma unroll
            for (int j = 0; j < 4; ++j) {
                const float xa = acc[0][nt][j], xg = acc[1][nt][j];
                const float th = 1.f - 2.f * __builtin_amdgcn_rcpf(__expf(2.f * xa) + 1.f);
                const float sg = __builtin_amdgcn_rcpf(1.f + __expf(-xg));
                g4[j] = th * sg;
            }
            gw[nt] = (unsigned long long)pack2bf(g4[0], g4[1]) |
                     ((unsigned long long)pack2bf(g4[2], g4[3]) << 32);
        }
        __syncthreads();  // B2: all XS reads done

        // write gs (overlay XS): rows = pos 0..127, same swizzle
#pragma unroll
        for (int nt = 0; nt < 8; ++nt) {
            const int n = nt * 16 + lm;
            *(unsigned long long*)(smem + n * 256 + ((c0 * 2) ^ ((n & 15) << 4))) = gw[nt];
        }

        // ---- issue tile1 prefetch, half 2 (h=1): hides under 1x1 phase
        if (tt == 0) {
            const float* xb1 = xbase + l0b + LT;
#pragma unroll
            for (int p = 0; p < 2; ++p)
#pragma unroll
                for (int c = 0; c < 8; ++c)
                    pf1[p * 8 + c] = xb1[(size_t)(wv * 16 + 8 + c) * LL + lane + p * 64];
        }
        __syncthreads();  // B3: gs ready

        // ---- 1x1 conv: y[128][128] = w1[128][128] @ g
        f32x4 acc2[8];
#pragma unroll
        for (int nt = 0; nt < 8; ++nt) acc2[nt] = (f32x4){0.f, 0.f, 0.f, 0.f};
#pragma unroll
        for (int kc = 0; kc < 4; ++kc) {
#pragma unroll
            for (int nt = 0; nt < 8; ++nt) {
                const int n = nt * 16 + lm;
                const bh8 bf = *(const bh8*)(smem + n * 256 +
                                             (((kc * 32 + kg * 8) * 2) ^ ((n & 15) << 4)));
                acc2[nt] = __builtin_amdgcn_mfma_f32_16x16x32_bf16(w1f[kc], bf, acc2[nt], 0, 0, 0);
            }
        }
        __syncthreads();  // B4: all gs reads done

        // ---- marshal final out = (y + bias + x)*sqrt(0.5) as bf16 into YS
        const float4 bias4 = *(const float4*)(obias + c0);
        const float bias[4] = {bias4.x, bias4.y, bias4.z, bias4.w};
#pragma unroll
        for (int nt = 0; nt < 8; ++nt) {
            const int n = nt * 16 + lm;
            float o4[4];
#pragma unroll
            for (int j = 0; j < 4; ++j)
                o4[j] = (acc2[nt][j] + bias[j] +
                         b2f((unsigned int)(xr[nt] >> (16 * j)) & 0xffffu))
                        * 0.70710678118654752f;
            *(unsigned long long*)(smem + n * 264 + c0 * 2) =
                (unsigned long long)pack2bf(o4[0], o4[1]) |
                ((unsigned long long)pack2bf(o4[2], o4[3]) << 32);
        }
        __syncthreads();  // B5: ys ready

        // ---- epilogue: 8 packed b64 reads + 8 coalesced float4 stores
        {
            const int p4 = t & 31;      // pos group: p4*4..+3
            const int cb = t >> 5;      // 0..15: channel groups cb*4 and cb*4+64
            float* ob = out + (size_t)b * IC * LL + l0 + p4 * 4;
#pragma unroll
            for (int h = 0; h < 2; ++h) {
                const int chb = cb * 4 + h * 64;
                unsigned long long yq[4];
#pragma unroll
                for (int q = 0; q < 4; ++q)
                    yq[q] = *(const unsigned long long*)(smem + (p4 * 4 + q) * 264 + chb * 2);
#pragma unroll
                for (int e = 0; e < 4; ++e) {
                    float4 ov;
                    ov.x = b2f((unsigned int)(yq[0] >> (16 * e)) & 0xffffu);
                    ov.y = b2f((unsigned int)(yq[1] >> (16 * e)) & 0xffffu);
                    ov.z = b2f((unsigned int)(yq[2] >> (16 * e)) & 0xffffu);
                    ov.w = b2f((unsigned int)(yq[3] >> (16 * e)) & 0xffffu);
                    *(float4*)(ob + (size_t)(chb + e) * LL) = ov;
                }
            }
        }
    }
}

extern "C" void kernel_launch(void* const* d_in, const int* in_sizes, int n_in,
                              void* d_out, int out_size, void* d_ws, size_t ws_size,
                              hipStream_t stream) {
    (void)in_sizes; (void)n_in; (void)out_size; (void)ws_size;
    const float* x        = (const float*)d_in[0];
    const float* style    = (const float*)d_in[1];
    const float* conv_w   = (const float*)d_in[2];
    const float* mod_w    = (const float*)d_in[3];
    const float* mod_b    = (const float*)d_in[4];
    const float* out_v    = (const float*)d_in[5];
    const float* out_g    = (const float*)d_in[6];
    const float* out_bias = (const float*)d_in[7];
    float* out = (float*)d_out;

    float* s_buf = (float*)((char*)d_ws + WS_S_OFF);
    unsigned short* wbf  = (unsigned short*)((char*)d_ws + WS_W_OFF);
    unsigned short* w1bf = (unsigned short*)((char*)d_ws + WS_W1_OFF);

    k_style<<<dim3(B_), 128, 0, stream>>>(style, mod_w, mod_b, s_buf);
    k_modw<<<dim3(OC, B_), 128, 0, stream>>>(conv_w, s_buf, wbf);
    k_w1<<<dim3(RC), 128, 0, stream>>>(out_v, out_g, w1bf);
    k_main<<<dim3(B_ * LL / (LT * NT_)), 512, 0, stream>>>(x, wbf, w1bf, out_bias, out);
}

// Round 8
// 123.907 us; speedup vs baseline: 2.4753x; 2.4753x over previous
//
#include <hip/hip_runtime.h>
#include <hip/hip_bf16.h>
#include <math.h>

typedef float f32x4 __attribute__((ext_vector_type(4)));
typedef short bh8  __attribute__((ext_vector_type(8)));
typedef unsigned int u32x4 __attribute__((ext_vector_type(4)));

#define B_   16
#define IC   128
#define OC   256
#define RC   128
#define STY  512
#define KS_  3
#define LL   16384
#define LT   128

// ws layout (bytes)
#define WS_S_OFF   0
#define WS_W_OFF   8192
#define WS_W1_OFF  (8192 + 3145728)

// LDS: xs bf16, rows 0..129 = pos l0-1 .. l0+128, stride 256B, XOR ((row&15)<<4).
// gs (rows 0..127, same stride/swizzle) overlays xs after B2. No ys buffer.
#define SMEM_BYTES 33280

__device__ __forceinline__ unsigned short f2b(float f) {
    union { float f; unsigned int u; } z; z.f = f;
    unsigned int u = z.u;
    return (unsigned short)((u + 0x7fffu + ((u >> 16) & 1u)) >> 16);
}

__device__ __forceinline__ float b2f(unsigned int u16) {
    union { unsigned int u; float f; } z; z.u = u16 << 16;
    return z.f;
}

__device__ __forceinline__ unsigned int pack2bf(float a, float b) {
    __hip_bfloat162 p = __float22bfloat162_rn(make_float2(a, b));
    return *(unsigned int*)&p;
}

// ---------------- prologue 1: s[b][i] = style @ (mod_weight*scale).T + bias ----
__global__ void k_style(const float* __restrict__ style, const float* __restrict__ mw,
                        const float* __restrict__ mb, float* __restrict__ s_out) {
    const int b = blockIdx.x, i = threadIdx.x;
    const float4* st = (const float4*)(style + b * STY);
    const float4* w  = (const float4*)(mw + (size_t)i * STY);
    float acc = 0.f;
#pragma unroll 4
    for (int j = 0; j < STY / 4; ++j) {
        float4 a = st[j], c = w[j];
        acc += a.x * c.x + a.y * c.y + a.z * c.z + a.w * c.w;
    }
    s_out[b * IC + i] = acc * 0.044194173824159216f + mb[i];  // 1/sqrt(512)
}

// ---------------- prologue 2: modulated+demodulated bf16 weights ---------------
// wbf[b][o][tap*128 + i]
__global__ void k_modw(const float* __restrict__ cw, const float* __restrict__ s,
                       unsigned short* __restrict__ wbf) {
    const int o = blockIdx.x, b = blockIdx.y, i = threadIdx.x;
    const float sv = s[b * IC + i] * 0.029462782549439476f;  // 1/sqrt(128*9)
    const float w0 = cw[(o * IC + i) * KS_ + 0] * sv;
    const float w1 = cw[(o * IC + i) * KS_ + 1] * sv;
    const float w2 = cw[(o * IC + i) * KS_ + 2] * sv;
    float ss = w0 * w0 + w1 * w1 + w2 * w2;
    for (int off = 32; off; off >>= 1) ss += __shfl_down(ss, off, 64);
    __shared__ float red[2];
    if ((i & 63) == 0) red[i >> 6] = ss;
    __syncthreads();
    const float d = rsqrtf(red[0] + red[1] + 1e-8f);
    unsigned short* dst = wbf + ((size_t)b * OC + o) * 384 + i;
    dst[0]   = f2b(w0 * d);
    dst[128] = f2b(w1 * d);
    dst[256] = f2b(w2 * d);
}

// ---------------- prologue 3: weight-normed 1x1 matrix, pre-scaled by sqrt(.5) --
__global__ void k_w1(const float* __restrict__ v, const float* __restrict__ g,
                     unsigned short* __restrict__ w1bf) {
    const int o = blockIdx.x, c = threadIdx.x;
    const float vv = v[o * RC + c];
    float ss = vv * vv;
    for (int off = 32; off; off >>= 1) ss += __shfl_down(ss, off, 64);
    __shared__ float red[2];
    if ((c & 63) == 0) red[c >> 6] = ss;
    __syncthreads();
    w1bf[o * RC + c] = f2b(g[o] * vv * rsqrtf(red[0] + red[1]) * 0.70710678118654752f);
}

// ---------------- main fused kernel -------------------------------------------
__global__ __launch_bounds__(512, 4) void k_main(
    const float* __restrict__ x, const unsigned short* __restrict__ wbf,
    const unsigned short* __restrict__ w1bf, const float* __restrict__ obias,
    float* __restrict__ out) {
    __shared__ alignas(16) char smem[SMEM_BYTES];

    const int t = threadIdx.x;
    const int lane = t & 63, wv = t >> 6;
    const int lm = lane & 15, kg = lane >> 4;
    const int c0 = wv * 16 + kg * 4;

    // ---- XCD-aware remap: XCD k owns batches {2k,2k+1}
    const int lid = blockIdx.x;                       // 0..2047
    const int swz = (lid & 7) * 256 + (lid >> 3);
    const int b  = swz >> 7;            // batch
    const int l0 = (swz & 127) * LT;    // L-tile origin

    const float* xb = x + (size_t)b * IC * LL + l0;

    // ---- stage x: pos->lane (2 pos/lane), packed b128 writes
    {
        const int chb = wv * 16;
#pragma unroll
        for (int p = 0; p < 2; ++p) {
            const int pos = lane + p * 64;
            const int row = pos + 1;
#pragma unroll
            for (int h = 0; h < 2; ++h) {
                float xv[8];
#pragma unroll
                for (int c = 0; c < 8; ++c)
                    xv[c] = xb[(size_t)(chb + h * 8 + c) * LL + pos];
                u32x4 wvec;
                wvec.x = pack2bf(xv[0], xv[1]);
                wvec.y = pack2bf(xv[2], xv[3]);
                wvec.z = pack2bf(xv[4], xv[5]);
                wvec.w = pack2bf(xv[6], xv[7]);
                *(u32x4*)(smem + row * 256 +
                          (((chb + h * 8) * 2) ^ ((row & 15) << 4))) = wvec;
            }
        }
    }
    if (t < 128) {  // halo: row 0 = l0-1, row 129 = l0+128; ch = t
        const float* hx = x + ((size_t)b * IC + t) * LL;
        float lf = (l0 > 0) ? hx[l0 - 1] : 0.f;
        float rt = (l0 + LT < LL) ? hx[l0 + LT] : 0.f;
        *(unsigned short*)(smem + 0 * 256 + ((t * 2) ^ ((0 & 15) << 4)))     = f2b(lf);
        *(unsigned short*)(smem + 129 * 256 + ((t * 2) ^ ((129 & 15) << 4))) = f2b(rt);
    }
    __syncthreads();  // B1: xs ready

    // ---- conv: M-tiles [16wv,+16) (xa) and [128+16wv,+16) (xb), N=128, K=384
    f32x4 acc[2][8];
#pragma unroll
    for (int m = 0; m < 2; ++m)
#pragma unroll
        for (int nt = 0; nt < 8; ++nt) acc[m][nt] = (f32x4){0.f, 0.f, 0.f, 0.f};

    const unsigned short* wa = wbf + ((size_t)b * OC + wv * 16 + lm) * 384 + kg * 8;
    const unsigned short* wb2 = wa + 128 * 384;

    // 2-deep A-operand pipeline: load kc+1 while MFMAing kc
    bh8 ca0 = *(const bh8*)(wa + 0);
    bh8 ca1 = *(const bh8*)(wb2 + 0);
#pragma unroll
    for (int kc = 0; kc < 12; ++kc) {
        bh8 na0 = ca0, na1 = ca1;
        if (kc < 11) {
            const int nkoff = ((kc + 1) >> 2) * 128 + ((kc + 1) & 3) * 32;
            na0 = *(const bh8*)(wa + nkoff);
            na1 = *(const bh8*)(wb2 + nkoff);
        }
        const int tap = kc >> 2;
        const int icb = (kc & 3) * 32;
#pragma unroll
        for (int nt = 0; nt < 8; ++nt) {
            const int lr = nt * 16 + lm + tap;
            const bh8 bf = *(const bh8*)(smem + lr * 256 +
                                         (((icb + kg * 8) * 2) ^ ((lr & 15) << 4)));
            acc[0][nt] = __builtin_amdgcn_mfma_f32_16x16x32_bf16(ca0, bf, acc[0][nt], 0, 0, 0);
            acc[1][nt] = __builtin_amdgcn_mfma_f32_16x16x32_bf16(ca1, bf, acc[1][nt], 0, 0, 0);
        }
        ca0 = na0; ca1 = na1;
    }

    // ---- residual + bias, pre-scaled: cin[m][j] = (x[ch][pos] + bias[ch])*sqrt(.5)
    // New epilogue layout: this thread owns channel ch = wv*16+lm, positions m*16+kg*4+j.
    const int myc = wv * 16 + lm;
    const float bias = obias[myc];
    f32x4 cin[8];
#pragma unroll
    for (int m = 0; m < 8; ++m) {
#pragma unroll
        for (int j = 0; j < 4; ++j) {
            const int row = m * 16 + kg * 4 + j + 1;
            const unsigned short xu = *(const unsigned short*)(
                smem + row * 256 + ((myc * 2) ^ ((row & 15) << 4)));
            cin[m][j] = (b2f(xu) + bias) * 0.70710678118654752f;
        }
    }

    // ---- 1x1 weights (pre-scaled by sqrt(.5))
    const unsigned short* w1p = w1bf + (size_t)myc * RC + kg * 8;
    bh8 w1f[4];
#pragma unroll
    for (int kc = 0; kc < 4; ++kc) w1f[kc] = *(const bh8*)(w1p + kc * 32);

    // ---- gated tanh-sigmoid in registers
    unsigned long long gw[8];
#pragma unroll
    for (int nt = 0; nt < 8; ++nt) {
        float g4[4];
#pragma unroll
        for (int j = 0; j < 4; ++j) {
            const float xa = acc[0][nt][j], xg = acc[1][nt][j];
            const float th = 1.f - 2.f * __builtin_amdgcn_rcpf(__expf(2.f * xa) + 1.f);
            const float sg = __builtin_amdgcn_rcpf(1.f + __expf(-xg));
            g4[j] = th * sg;
        }
        gw[nt] = (unsigned long long)pack2bf(g4[0], g4[1]) |
                 ((unsigned long long)pack2bf(g4[2], g4[3]) << 32);
    }
    __syncthreads();  // B2: all xs reads (conv + residual) done

    // write gs (overlay xs): rows = pos 0..127, same swizzle
#pragma unroll
    for (int nt = 0; nt < 8; ++nt) {
        const int n = nt * 16 + lm;
        *(unsigned long long*)(smem + n * 256 + ((c0 * 2) ^ ((n & 15) << 4))) = gw[nt];
    }
    __syncthreads();  // B3: gs ready

    // ---- 1x1 conv, swapped operands: A=g (M=pos), B=w1' (N=ch), C-in=(x+bias)*s
    // Output fragment: lane holds 4 consecutive positions of channel myc -> float4 store.
    float* orow = out + ((size_t)b * IC + myc) * LL + l0 + kg * 4;
#pragma unroll
    for (int m = 0; m < 8; ++m) {
        f32x4 acc2 = cin[m];
#pragma unroll
        for (int kc = 0; kc < 4; ++kc) {
            const int n = m * 16 + lm;
            const bh8 ga = *(const bh8*)(smem + n * 256 +
                                         (((kc * 32 + kg * 8) * 2) ^ ((n & 15) << 4)));
            acc2 = __builtin_amdgcn_mfma_f32_16x16x32_bf16(ga, w1f[kc], acc2, 0, 0, 0);
        }
        float4 ov;
        ov.x = acc2[0]; ov.y = acc2[1]; ov.z = acc2[2]; ov.w = acc2[3];
        *(float4*)(orow + m * 16) = ov;
    }
}

extern "C" void kernel_launch(void* const* d_in, const int* in_sizes, int n_in,
                              void* d_out, int out_size, void* d_ws, size_t ws_size,
                              hipStream_t stream) {
    (void)in_sizes; (void)n_in; (void)out_size; (void)ws_size;
    const float* x        = (const float*)d_in[0];
    const float* style    = (const float*)d_in[1];
    const float* conv_w   = (const float*)d_in[2];
    const float* mod_w    = (const float*)d_in[3];
    const float* mod_b    = (const float*)d_in[4];
    const float* out_v    = (const float*)d_in[5];
    const float* out_g    = (const float*)d_in[6];
    const float* out_bias = (const float*)d_in[7];
    float* out = (float*)d_out;

    float* s_buf = (float*)((char*)d_ws + WS_S_OFF);
    unsigned short* wbf  = (unsigned short*)((char*)d_ws + WS_W_OFF);
    unsigned short* w1bf = (unsigned short*)((char*)d_ws + WS_W1_OFF);

    k_style<<<dim3(B_), 128, 0, stream>>>(style, mod_w, mod_b, s_buf);
    k_modw<<<dim3(OC, B_), 128, 0, stream>>>(conv_w, s_buf, wbf);
    k_w1<<<dim3(RC), 128, 0, stream>>>(out_v, out_g, w1bf);
    k_main<<<dim3(B_ * LL / LT), 512, 0, stream>>>(x, wbf, w1bf, out_bias, out);
}